// Round 4
// baseline (90.063 us; speedup 1.0000x reference)
//
#include <hip/hip_runtime.h>
#include <math.h>

#define NPTS   4096
#define NB     8
#define IT     4                           // i-points per lane
#define IGRP   (64 * IT)                   // 256 i-points per block
#define JSPLIT 4
#define JBLK   (NPTS / JSPLIT)             // 1024 j-points per block
#define NWAVES 8
#define BLK    (NWAVES * 64)               // 512 threads
#define JCHUNK (JBLK / NWAVES)             // 128 j per wave
#define INV_H2 (1.0f / (0.03f * 0.03f))
#define INFD   3.0e38f

__device__ __forceinline__ float med3f(float a, float b, float c) {
#if defined(__has_builtin)
#if __has_builtin(__builtin_amdgcn_fmed3f)
  return __builtin_amdgcn_fmed3f(a, b, c);
#else
  return fminf(c, fmaxf(a, b));
#endif
#else
  return fminf(c, fmaxf(a, b));
#endif
}

// lowest-4 (ascending) of two ascending 4-lists.
__device__ __forceinline__ float4 merge4(float4 A, float4 B) {
  float L0 = fminf(A.x, B.w), L1 = fminf(A.y, B.z);
  float L2 = fminf(A.z, B.y), L3 = fminf(A.w, B.x);
  float e0 = fminf(L0, L2), e2 = fmaxf(L0, L2);
  float e1 = fminf(L1, L3), e3 = fmaxf(L1, L3);
  return make_float4(fminf(e0, e1), fmaxf(e0, e1), fminf(e2, e3), fmaxf(e2, e3));
}

// Scan LDS j-points [lo,hi). Shifted domain u = ||q||^2 - 2 p_i.q (monotone in d;
// + ||p_i||^2 is applied once in k2). 7 VALU/pair: 3 fma + 4-op sorted insert.
// One broadcast ds_read_b128 feeds 4 i-points per lane = 256 pairs/wave-iter.
template <bool CHECK>
__device__ __forceinline__ void scan_range(const float4* __restrict__ sP,
                                           int lo, int hi, const int* __restrict__ ls,
                                           const float* __restrict__ mx,
                                           const float* __restrict__ my,
                                           const float* __restrict__ mz,
                                           float t[IT][4]) {
#pragma unroll 4
  for (int j = lo; j < hi; ++j) {
    float4 q = sP[j];                        // wave-uniform addr -> broadcast
#pragma unroll
    for (int s = 0; s < IT; ++s) {
      float u = fmaf(mz[s], q.z, q.w);       // q.w = ||q||^2
      u = fmaf(my[s], q.y, u);
      u = fmaf(mx[s], q.x, u);
      if (CHECK) u = (j == ls[s]) ? INFD : u;  // self-exclusion (rare blocks only)
      t[s][3] = med3f(t[s][2], u, t[s][3]);
      t[s][2] = med3f(t[s][1], u, t[s][2]);
      t[s][1] = med3f(t[s][0], u, t[s][1]);
      t[s][0] = fminf(t[s][0], u);
    }
  }
}

// K1: block = (batch b, i-group g of 256, j-quarter js). Stages 1024 j-points
// (16 KB), scans, writes one sorted partial 4-list per i-point to ws.
__global__ __launch_bounds__(BLK)
void repulsion_k1(const float* __restrict__ pc, float4* __restrict__ ws) {
  __shared__ float4 buf[2 * JBLK];           // 32 KB union: sP (first 1024) then cand (2048)
  float4* sP = buf;

  const int blk = blockIdx.x;
  const int b   = blk >> 6;
  const int g   = (blk >> 2) & 15;
  const int js  = blk & 3;
  const int tid = threadIdx.x;
  const float* base = pc + (size_t)b * NPTS * 3;

  // Stage j-quarter into LDS with ||q||^2: 256 threads x 3 float4 -> 4 points.
  if (tid < JBLK / 4) {
    const float4* pcv = (const float4*)base + (size_t)js * (JBLK * 3 / 4);
    float4 a = pcv[3 * tid + 0];
    float4 c = pcv[3 * tid + 1];
    float4 e = pcv[3 * tid + 2];
    float x0 = a.x, y0 = a.y, z0 = a.z;
    float x1 = a.w, y1 = c.x, z1 = c.y;
    float x2 = c.z, y2 = c.w, z2 = e.x;
    float x3 = e.y, y3 = e.z, z3 = e.w;
    sP[4 * tid + 0] = make_float4(x0, y0, z0, fmaf(x0, x0, fmaf(y0, y0, z0 * z0)));
    sP[4 * tid + 1] = make_float4(x1, y1, z1, fmaf(x1, x1, fmaf(y1, y1, z1 * z1)));
    sP[4 * tid + 2] = make_float4(x2, y2, z2, fmaf(x2, x2, fmaf(y2, y2, z2 * z2)));
    sP[4 * tid + 3] = make_float4(x3, y3, z3, fmaf(x3, x3, fmaf(y3, y3, z3 * z3)));
  }

  const int w    = tid >> 6;
  const int lane = tid & 63;

  // Load this lane's 4 i-points from global (L2/L3-hot), premultiply -2*p.
  float mx[IT], my[IT], mz[IT];
  int ls[IT];
#pragma unroll
  for (int s = 0; s < IT; ++s) {
    int gi = g * IGRP + lane + 64 * s;
    float x = base[3 * gi + 0];
    float y = base[3 * gi + 1];
    float z = base[3 * gi + 2];
    mx[s] = -2.0f * x; my[s] = -2.0f * y; mz[s] = -2.0f * z;
    ls[s] = gi - js * JBLK;                  // local self index (may be out of range)
  }

  float t[IT][4];
#pragma unroll
  for (int s = 0; s < IT; ++s) { t[s][0] = INFD; t[s][1] = INFD; t[s][2] = INFD; t[s][3] = INFD; }

  __syncthreads();

  const int lo = w * JCHUNK, hi = lo + JCHUNK;
  // Self-indices live in this block iff js == g>>2; then only waves with
  // (w>>1) == (g&3) have them in their 128-chunk.
  const bool chk = (js == (g >> 2)) && ((w >> 1) == (g & 3));
  if (chk) scan_range<true >(sP, lo, hi, ls, mx, my, mz, t);
  else     scan_range<false>(sP, lo, hi, ls, mx, my, mz, t);

  __syncthreads();                           // all reads of sP done; reuse LDS as cand
  float4* cand = buf;
#pragma unroll
  for (int s = 0; s < IT; ++s)
    cand[w * IGRP + lane + 64 * s] = make_float4(t[s][0], t[s][1], t[s][2], t[s][3]);
  __syncthreads();

  // Merge the 8 waves' sorted 4-lists per i-point; threads 0..255, one i each.
  if (tid < IGRP) {
    float4 L[NWAVES];
#pragma unroll
    for (int ww = 0; ww < NWAVES; ++ww) L[ww] = cand[ww * IGRP + tid];
#pragma unroll
    for (int ww = 0; ww < 4; ++ww) L[ww] = merge4(L[2 * ww], L[2 * ww + 1]);
    L[0] = merge4(L[0], L[1]);
    L[1] = merge4(L[2], L[3]);
    float4 R = merge4(L[0], L[1]);           // sorted ascending partial 4-list
    int gi = b * NPTS + g * IGRP + tid;      // global point id
    ws[(size_t)gi * JSPLIT + js] = R;
  }
}

// K2: per point, merge the JSPLIT partial lists, add ||p||^2, clamp, exp, reduce.
__global__ __launch_bounds__(256)
void repulsion_k2(const float* __restrict__ pc, const float4* __restrict__ ws,
                  float* __restrict__ out) {
  const int t = blockIdx.x * 256 + threadIdx.x;   // 0..32767 global point id
  const float4* w4 = ws + (size_t)t * JSPLIT;
  float4 L0 = w4[0], L1 = w4[1], L2 = w4[2], L3 = w4[3];
  float4 A = merge4(L0, L1);
  float4 Bv = merge4(L2, L3);
  float f0 = fminf(A.x, Bv.w);
  float f1 = fminf(A.y, Bv.z);
  float f2 = fminf(A.z, Bv.y);
  float f3 = fminf(A.w, Bv.x);

  float x = pc[3 * t + 0], y = pc[3 * t + 1], z = pc[3 * t + 2];
  float sqi = fmaf(x, x, fmaf(y, y, z * z));

  float s = 0.0f;
  float m;
  m = fmaxf(f0 + sqi, 0.0f); s -= m * expf(-m * INV_H2);
  m = fmaxf(f1 + sqi, 0.0f); s -= m * expf(-m * INV_H2);
  m = fmaxf(f2 + sqi, 0.0f); s -= m * expf(-m * INV_H2);
  m = fmaxf(f3 + sqi, 0.0f); s -= m * expf(-m * INV_H2);

  for (int off = 32; off > 0; off >>= 1) s += __shfl_down(s, off);
  if ((threadIdx.x & 63) == 0) atomicAdd(out, s);
}

extern "C" void kernel_launch(void* const* d_in, const int* in_sizes, int n_in,
                              void* d_out, int out_size, void* d_ws, size_t ws_size,
                              hipStream_t stream) {
  const float* pc = (const float*)d_in[0];
  float* out = (float*)d_out;
  float4* ws = (float4*)d_ws;                // 32768 * 4 * 16 B = 2 MB used
  hipMemsetAsync(out, 0, sizeof(float), stream);
  repulsion_k1<<<dim3(NB * 16 * JSPLIT), dim3(BLK), 0, stream>>>(pc, ws);
  repulsion_k2<<<dim3(NB * NPTS / 256), dim3(256), 0, stream>>>(pc, ws, out);
}